// Round 10
// baseline (853.157 us; speedup 1.0000x reference)
//
#include <hip/hip_runtime.h>
#include <math.h>

typedef _Float16 h8_t __attribute__((ext_vector_type(8)));
typedef _Float16 h4_t __attribute__((ext_vector_type(4)));
typedef float f4_t __attribute__((ext_vector_type(4)));

// Linear LDS tiles: [R][32] halfs, row stride 64 B (m97-validated pattern).

// fast sigmoid / tanh using native v_exp_f32 + v_rcp_f32.
__device__ __forceinline__ float fsig(float x) {
  return __builtin_amdgcn_rcpf(1.f + __expf(-x));
}
__device__ __forceinline__ float ftanh(float x) {
  float e = __expf(-2.f * fabsf(x));
  float t = (1.f - e) * __builtin_amdgcn_rcpf(1.f + e);
  return copysignf(t, x);
}

// XCD-aware bijective block swizzle (T1): hardware round-robins linear block
// ids across 8 XCDs; remap so each XCD executes a CONTIGUOUS chunk of work.
// All perf-critical grids here are divisible by 8; identity fallback otherwise.
__device__ __forceinline__ int xcd_swz_lin(int lin, int nwg) {
  if (nwg & 7) return lin;
  int cpx = nwg >> 3;
  return (lin & 7) * cpx + (lin >> 3);
}

// async global->LDS, 16 B per lane. LDS dest must be wave-uniform base +
// lane*16; our callers pass base + tid*16 which satisfies that identity.
__device__ __forceinline__ void gload16(const _Float16* g, _Float16* l) {
  __builtin_amdgcn_global_load_lds(
      (const __attribute__((address_space(1))) void*)g,
      (__attribute__((address_space(3))) void*)l, 16, 0, 0);
}

// stage R rows x 32 halfs from f16 source (row stride ld halfs) into linear
// LDS [R][32] via global_load_lds. 256 threads. LDS offset = idx*16 B equals
// row*64 + (idx&3)*16 exactly (row = idx>>2), so layout is linear [R][32].
template <int R>
__device__ __forceinline__ void gstage(const _Float16* __restrict__ src, int ld,
                                       _Float16* __restrict__ dst, int t) {
#pragma unroll
  for (int it = 0; it < R / 64; ++it) {
    int idx = t + it * 256;       // 0..R*4-1
    int row = idx >> 2;           // 0..R-1
    int kq  = (idx & 3) << 3;     // 0,8,16,24 halfs
    gload16(src + (size_t)row * ld + kq, dst + (size_t)idx * 8);
  }
}

// T14 async-STAGE split for the reg-staged fp32 A-path.
// loadA: issue the float4 global loads into registers. PLACEMENT MATTERS:
// must be issued AFTER barrier2 / before the MFMA cluster, so the loads
// complete under the MFMA window — hipcc drains vmcnt(0) at every
// s_barrier, so loads issued just before a barrier get zero overlap.
// writeA: cvt fp32->f16 + ds_write into linear LDS [R][32] (write-late,
// after the NEXT iteration's barrier1 has drained the loads).
// Same element order/converts as the fused stage -> bitwise identical.
template <int R>
__device__ __forceinline__ void loadA_f32(const float* __restrict__ src, int ld,
                                          int t, float4* v) {
#pragma unroll
  for (int it = 0; it < R / 32; ++it) {
    int idx = t + it * 256;       // 0..R*8-1
    int row = idx >> 3;           // 0..R-1
    int kg  = (idx & 7) << 2;     // 0,4,..,28
    v[it] = *(const float4*)(src + (size_t)row * ld + kg);
  }
}
template <int R>
__device__ __forceinline__ void writeA_f16(_Float16* __restrict__ dst, int t,
                                           const float4* v) {
#pragma unroll
  for (int it = 0; it < R / 32; ++it) {
    int idx = t + it * 256;
    int row = idx >> 3;
    int kg  = (idx & 7) << 2;
    h4_t h = {(_Float16)v[it].x, (_Float16)v[it].y,
              (_Float16)v[it].z, (_Float16)v[it].w};
    *(h4_t*)(dst + row * 32 + kg) = h;
  }
}

// Convert the 4 weight matrices fp32 -> f16 (one launch)
__global__ __launch_bounds__(256) void convert_weights(
    const float* __restrict__ Wioux, const float* __restrict__ Wiouh,
    const float* __restrict__ Wfx, const float* __restrict__ Wfh,
    _Float16* __restrict__ Wx, _Float16* __restrict__ Wh,
    _Float16* __restrict__ Wfxh, _Float16* __restrict__ Wfhh)
{
  int i4 = (blockIdx.x * 256 + threadIdx.x) * 4;   // < 786432
  const float* src; _Float16* dst; int off;
  if (i4 < 393216)      { src = Wioux; dst = Wx;   off = i4; }
  else if (i4 < 589824) { src = Wiouh; dst = Wh;   off = i4 - 393216; }
  else if (i4 < 720896) { src = Wfx;   dst = Wfxh; off = i4 - 589824; }
  else                  { src = Wfh;   dst = Wfhh; off = i4 - 720896; }
  float4 v = *(const float4*)(src + off);
  h4_t h = {(_Float16)v.x, (_Float16)v.y, (_Float16)v.z, (_Float16)v.w};
  *(h4_t*)(dst + off) = h;
}

// fx = x @ Wfx.T  for nodes 0..72 (rows = 73*256), fp32 out, no bias.
// 64-row x FULL 256-col tile (A staged once), 4 waves in 2x2,
// each wave 32 rows x 128 cols. T14 split-stage on A (post-barrier2 issue).
__global__ __launch_bounds__(256) void fx_gemm(
    const float* __restrict__ x, const _Float16* __restrict__ Wfx,
    float* __restrict__ out)
{
  __shared__ _Float16 As[64 * 32];
  __shared__ _Float16 Bs[256 * 32];
  const int t = threadIdx.x;
  int swz = xcd_swz_lin(blockIdx.x, gridDim.x);
  const int r0 = swz * 64;
  const int w = t >> 6, lane = t & 63;
  const int wr = (w >> 1) * 32, wc = (w & 1) * 128;
  const int fr = lane & 15, fq = (lane >> 4) * 8;
  f4_t acc[2][8] = {};
  float4 va[2], vn[2];
  loadA_f32<64>(x + (size_t)r0 * 512, 512, t, va);
  for (int k0 = 0; k0 < 512; k0 += 32) {
    __syncthreads();
    writeA_f16<64>(As, t, va);
    gstage<256>(Wfx + (size_t)k0, 512, Bs, t);
    __syncthreads();
    // issue next A-loads here: they complete under the MFMA cluster below
    if (k0 + 32 < 512)
      loadA_f32<64>(x + (size_t)r0 * 512 + k0 + 32, 512, t, vn);
    h8_t a[2], b[8];
#pragma unroll
    for (int rt = 0; rt < 2; ++rt)
      a[rt] = *(const h8_t*)(As + (wr + rt * 16 + fr) * 32 + fq);
#pragma unroll
    for (int ct = 0; ct < 8; ++ct)
      b[ct] = *(const h8_t*)(Bs + (wc + ct * 16 + fr) * 32 + fq);
#pragma unroll
    for (int rt = 0; rt < 2; ++rt)
#pragma unroll
      for (int ct = 0; ct < 8; ++ct)
        acc[rt][ct] = __builtin_amdgcn_mfma_f32_16x16x32_f16(a[rt], b[ct], acc[rt][ct], 0, 0, 0);
    if (k0 + 32 < 512) { va[0] = vn[0]; va[1] = vn[1]; }
  }
#pragma unroll
  for (int rt = 0; rt < 2; ++rt)
#pragma unroll
    for (int ct = 0; ct < 8; ++ct)
#pragma unroll
      for (int i = 0; i < 4; ++i) {
        int row = wr + rt * 16 + (lane >> 4) * 4 + i;
        int col = wc + ct * 16 + (lane & 15);
        out[(size_t)(r0 + row) * 256 + col] = acc[rt][ct][i];
      }
}

// fh = h @ Wfh.T for one level's nodes (rows = L*256), f16 out, no bias.
// A is fp32 (h_out rows), ld 256, K=256. 64-row x FULL 256-col tile.
// T14 split-stage on A (post-barrier2 issue).
__global__ __launch_bounds__(256) void fh_gemm(
    const float* __restrict__ h_src, const _Float16* __restrict__ Wfh,
    _Float16* __restrict__ out)
{
  __shared__ _Float16 As[64 * 32];
  __shared__ _Float16 Bs[256 * 32];
  const int t = threadIdx.x;
  int swz = xcd_swz_lin(blockIdx.x, gridDim.x);
  const int r0 = swz * 64;
  const int w = t >> 6, lane = t & 63;
  const int wr = (w >> 1) * 32, wc = (w & 1) * 128;
  const int fr = lane & 15, fq = (lane >> 4) * 8;
  f4_t acc[2][8] = {};
  float4 va[2], vn[2];
  loadA_f32<64>(h_src + (size_t)r0 * 256, 256, t, va);
  for (int k0 = 0; k0 < 256; k0 += 32) {
    __syncthreads();
    writeA_f16<64>(As, t, va);
    gstage<256>(Wfh + (size_t)k0, 256, Bs, t);
    __syncthreads();
    if (k0 + 32 < 256)
      loadA_f32<64>(h_src + (size_t)r0 * 256 + k0 + 32, 256, t, vn);
    h8_t a[2], b[8];
#pragma unroll
    for (int rt = 0; rt < 2; ++rt)
      a[rt] = *(const h8_t*)(As + (wr + rt * 16 + fr) * 32 + fq);
#pragma unroll
    for (int ct = 0; ct < 8; ++ct)
      b[ct] = *(const h8_t*)(Bs + (wc + ct * 16 + fr) * 32 + fq);
#pragma unroll
    for (int rt = 0; rt < 2; ++rt)
#pragma unroll
      for (int ct = 0; ct < 8; ++ct)
        acc[rt][ct] = __builtin_amdgcn_mfma_f32_16x16x32_f16(a[rt], b[ct], acc[rt][ct], 0, 0, 0);
    if (k0 + 32 < 256) { va[0] = vn[0]; va[1] = vn[1]; }
  }
#pragma unroll
  for (int rt = 0; rt < 2; ++rt)
#pragma unroll
    for (int ct = 0; ct < 8; ++ct)
#pragma unroll
      for (int i = 0; i < 4; ++i) {
        int row = wr + rt * 16 + (lane >> 4) * 4 + i;
        int col = wc + ct * 16 + (lane & 15);
        out[(size_t)(r0 + row) * 256 + col] = (_Float16)acc[rt][ct][i];
      }
}

// Fused: chs[nl,b,m] = f16( sum_j w_j * h[child_j] )  AND
// cacc[nl,b,m] = sum_j sigmoid(w_j*fh[child_j] + bfh + bfx + fx) * w_j * c[child_j]
// (f-gate GEMM hoisted by linearity: (w*h)@W = w*(h@W))
__global__ __launch_bounds__(256) void chs_fgate(
    const float* __restrict__ h_all, const _Float16* __restrict__ fh,
    const _Float16* __restrict__ c_half, const float* __restrict__ prob,
    const float* __restrict__ bfh, const float* __restrict__ bfx,
    const float* __restrict__ fxb, _Float16* __restrict__ chs,
    float* __restrict__ cacc, int s, int cs)
{
  int blk = xcd_swz_lin(blockIdx.x, gridDim.x);
  int idx = blk * 256 + threadIdx.x;   // over L*16384
  int m = (idx & 63) << 2;
  int b = (idx >> 6) & 255;
  int nl = idx >> 14;
  int node = s + nl;
  float4 vfx = *(const float4*)(fxb + ((size_t)node * 256 + b) * 256 + m);
  float4 vbh = *(const float4*)(bfh + m);
  float4 vbx = *(const float4*)(bfx + m);
  float b0 = vfx.x + vbh.x + vbx.x;
  float b1 = vfx.y + vbh.y + vbx.y;
  float b2 = vfx.z + vbh.z + vbx.z;
  float b3 = vfx.w + vbh.w + vbx.w;
  float4 hacc = {0.f, 0.f, 0.f, 0.f};
  float4 cc = {0.f, 0.f, 0.f, 0.f};
#pragma unroll
  for (int j = 0; j < 8; ++j) {
    int child = node * 8 + 1 + j;
    float wv = prob[node * 585 + child];
    float4 hv = *(const float4*)(h_all + (size_t)child * 65536 + b * 256 + m);
    hacc.x += wv * hv.x; hacc.y += wv * hv.y;
    hacc.z += wv * hv.z; hacc.w += wv * hv.w;
    h4_t fv = *(const h4_t*)(fh + (size_t)(child - cs) * 65536 + b * 256 + m);
    h4_t cv = *(const h4_t*)(c_half + (size_t)child * 65536 + b * 256 + m);
    cc.x += wv * (float)cv[0] * fsig(wv * (float)fv[0] + b0);
    cc.y += wv * (float)cv[1] * fsig(wv * (float)fv[1] + b1);
    cc.z += wv * (float)cv[2] * fsig(wv * (float)fv[2] + b2);
    cc.w += wv * (float)cv[3] * fsig(wv * (float)fv[3] + b3);
  }
  h4_t hc = {(_Float16)hacc.x, (_Float16)hacc.y, (_Float16)hacc.z, (_Float16)hacc.w};
  *(h4_t*)(chs + (size_t)nl * 65536 + b * 256 + m) = hc;
  *(float4*)(cacc + ((size_t)nl * 256 + b) * 256 + m) = cc;
}

// Fused iou GEMM + pointwise. Block owns 64 rows x (CT*32) m-cols across ALL
// 3 gates (i at m, o at 256+m, u at 512+m). CT = col-fragments per wave:
// CT=4 -> 128-col m-tile (grid.x=2), CT=2 -> 64-col m-tile (grid.x=4, used
// for small levels to raise block-parallelism on the serial tail).
// Phase 0: K=512 from x (fp32->f16, T14 split reg-stage with post-barrier2
// load issue); phase 1 (internal only): K=256 from chs (f16,
// global_load_lds). Weights via global_load_lds (L2-resident).
// Epilogue: c = sig(i)*tanh(u) + cacc, h = sig(o)*tanh(c); writes
// h_all(f32), c_half(f16). 4 waves in 2x2.
template <int CT>
__global__ __launch_bounds__(256) void iou_fused(
    const float* __restrict__ x, const _Float16* __restrict__ chs,
    const float* __restrict__ cacc,
    const _Float16* __restrict__ Wx, const _Float16* __restrict__ Wh,
    const float* __restrict__ bioux, const float* __restrict__ biouh,
    _Float16* __restrict__ c_half, float* __restrict__ h_all, int node0)
{
  __shared__ _Float16 As[64 * 32];
  __shared__ _Float16 Bs[3][CT * 32 * 32];
  const int t = threadIdx.x;
  int swz = xcd_swz_lin(blockIdx.y * gridDim.x + blockIdx.x,
                        gridDim.x * gridDim.y);
  const int m0 = (swz % gridDim.x) * (CT * 32);
  const int r0 = (swz / gridDim.x) * 64;
  const int w = t >> 6, lane = t & 63;
  const int wr = (w >> 1) * 32, wc = (w & 1) * (CT * 16);
  const int fr = lane & 15, fq = (lane >> 4) * 8;

  f4_t acc[3][2][CT] = {};
  for (int ph = 0; ph < 2; ++ph) {
    if (ph == 1 && chs == nullptr) break;
    const int K = ph ? 256 : 512;
    const _Float16* W = ph ? Wh : Wx;
    float4 va[2], vn[2];
    if (ph == 0) loadA_f32<64>(x + (size_t)r0 * 512, 512, t, va);
    for (int k0 = 0; k0 < K; k0 += 32) {
      __syncthreads();
      if (ph == 0) writeA_f16<64>(As, t, va);
      else         gstage<64>(chs + (size_t)r0 * 256 + k0, 256, As, t);
#pragma unroll
      for (int g = 0; g < 3; ++g)
        gstage<CT * 32>(W + (size_t)(g * 256 + m0) * K + k0, K, &Bs[g][0], t);
      __syncthreads();
      // issue next A-loads here: they complete under the MFMA cluster
      if (ph == 0 && k0 + 32 < K)
        loadA_f32<64>(x + (size_t)r0 * 512 + k0 + 32, 512, t, vn);
      h8_t a[2], b[3][CT];
#pragma unroll
      for (int rt = 0; rt < 2; ++rt)
        a[rt] = *(const h8_t*)(As + (wr + rt * 16 + fr) * 32 + fq);
#pragma unroll
      for (int g = 0; g < 3; ++g)
#pragma unroll
        for (int ct = 0; ct < CT; ++ct)
          b[g][ct] = *(const h8_t*)(&Bs[g][0] + (wc + ct * 16 + fr) * 32 + fq);
#pragma unroll
      for (int g = 0; g < 3; ++g)
#pragma unroll
        for (int rt = 0; rt < 2; ++rt)
#pragma unroll
          for (int ct = 0; ct < CT; ++ct)
            acc[g][rt][ct] = __builtin_amdgcn_mfma_f32_16x16x32_f16(a[rt], b[g][ct], acc[g][rt][ct], 0, 0, 0);
      if (ph == 0 && k0 + 32 < K) { va[0] = vn[0]; va[1] = vn[1]; }
    }
  }
#pragma unroll
  for (int rt = 0; rt < 2; ++rt)
#pragma unroll
    for (int ct = 0; ct < CT; ++ct)
#pragma unroll
      for (int i = 0; i < 4; ++i) {
        int row = wr + rt * 16 + (lane >> 4) * 4 + i;
        int col = wc + ct * 16 + (lane & 15);
        int m = m0 + col;
        size_t lrow = (size_t)(r0 + row);
        float iv = acc[0][rt][ct][i] + bioux[m] + biouh[m];
        float ov = acc[1][rt][ct][i] + bioux[256 + m] + biouh[256 + m];
        float uv = acc[2][rt][ct][i] + bioux[512 + m] + biouh[512 + m];
        float c = fsig(iv) * ftanh(uv) + (cacc ? cacc[lrow * 256 + m] : 0.f);
        float h = fsig(ov) * ftanh(c);
        size_t g = ((size_t)node0 * 256 + lrow) * 256 + m;
        h_all[g] = h;
        c_half[g] = (_Float16)c;
      }
}

extern "C" void kernel_launch(void* const* d_in, const int* in_sizes, int n_in,
                              void* d_out, int out_size, void* d_ws, size_t ws_size,
                              hipStream_t stream) {
  const float* inputs = (const float*)d_in[0];
  const float* prob   = (const float*)d_in[1];
  const float* Wioux  = (const float*)d_in[2];
  const float* bioux  = (const float*)d_in[3];
  const float* Wiouh  = (const float*)d_in[4];
  const float* biouh  = (const float*)d_in[5];
  const float* Wfx    = (const float*)d_in[6];
  const float* bfx    = (const float*)d_in[7];
  const float* Wfh    = (const float*)d_in[8];
  const float* bfh    = (const float*)d_in[9];
  float* h_out = (float*)d_out;

  char* p = (char*)d_ws;
  _Float16* c_half = (_Float16*)p; p += (size_t)585 * 65536 * 2;
  _Float16* fh     = (_Float16*)p; p += (size_t)512 * 65536 * 2;
  float*    fxb    = (float*)p;    p += (size_t)73 * 65536 * 4;
  _Float16* chs    = (_Float16*)p; p += (size_t)64 * 65536 * 2;
  float*    cacc   = (float*)p;    p += (size_t)64 * 65536 * 4;
  _Float16* Wx     = (_Float16*)p; p += (size_t)393216 * 2;
  _Float16* Wh     = (_Float16*)p; p += (size_t)196608 * 2;
  _Float16* Wfxh   = (_Float16*)p; p += (size_t)131072 * 2;
  _Float16* Wfhh   = (_Float16*)p; p += (size_t)65536 * 2;

  convert_weights<<<768, 256, 0, stream>>>(Wioux, Wiouh, Wfx, Wfh, Wx, Wh, Wfxh, Wfhh);
  // fx rows = 73*256 = 18688 = 292 * 64 ; full-M tile, A staged once
  fx_gemm<<<292, 256, 0, stream>>>(inputs, Wfxh, fxb);

  // leaves: nodes 73..584, rows = 512*256 = 2048 * 64 ; grid 4096
  iou_fused<4><<<dim3(2, 2048), 256, 0, stream>>>(
      inputs + (size_t)73 * 131072, nullptr, nullptr,
      Wx, Wh, bioux, biouh, c_half, h_out, 73);
  // fh for leaves (children of level 2), indexed node-73 ; full-M tile
  fh_gemm<<<2048, 256, 0, stream>>>(
      h_out + (size_t)73 * 65536, Wfhh, fh);

  // level 2 (s=9, L=64): big enough for wide tiles
  chs_fgate<<<64 * 64, 256, 0, stream>>>(
      h_out, fh, c_half, prob, bfh, bfx, fxb, chs, cacc, 9, 73);
  iou_fused<4><<<dim3(2, 256), 256, 0, stream>>>(
      inputs + (size_t)9 * 131072, chs, cacc,
      Wx, Wh, bioux, biouh, c_half, h_out, 9);
  fh_gemm<<<256, 256, 0, stream>>>(
      h_out + (size_t)9 * 65536, Wfhh, fh);

  // level 1 (s=1, L=8): narrow tiles for 2x block-parallelism on the tail
  chs_fgate<<<8 * 64, 256, 0, stream>>>(
      h_out, fh, c_half, prob, bfh, bfx, fxb, chs, cacc, 1, 9);
  iou_fused<2><<<dim3(4, 32), 256, 0, stream>>>(
      inputs + (size_t)1 * 131072, chs, cacc,
      Wx, Wh, bioux, biouh, c_half, h_out, 1);
  fh_gemm<<<32, 256, 0, stream>>>(
      h_out + (size_t)1 * 65536, Wfhh, fh);

  // level 0 (root, s=0, L=1)
  chs_fgate<<<64, 256, 0, stream>>>(
      h_out, fh, c_half, prob, bfh, bfx, fxb, chs, cacc, 0, 1);
  iou_fused<2><<<dim3(4, 4), 256, 0, stream>>>(
      inputs, chs, cacc,
      Wx, Wh, bioux, biouh, c_half, h_out, 0);
}